// Round 2
// baseline (65.686 us; speedup 1.0000x reference)
//
#include <hip/hip_runtime.h>

// BCE-sum reduction over 2×128MiB fp32 inputs → scalar.
// HBM floor ~21 µs (L3 serves ~half the 256 MiB working set; FETCH_SIZE
// measured 134 MB). R0 was latency-bound (VALUBusy 25%, hbm 16%): 2 loads
// in flight/thread, serial acc chain. Fix: unroll×4, batch 8 loads before
// compute, 4 independent accumulators.

__device__ __forceinline__ float bce4(float4 p, float4 t) {
    const float LOG_CLAMP = -100.0f;
    float s;
    float lp, l1mp;
    lp   = fmaxf(__logf(p.x),        LOG_CLAMP);
    l1mp = fmaxf(__logf(1.0f - p.x), LOG_CLAMP);
    s  = -(t.x * lp + (1.0f - t.x) * l1mp);
    lp   = fmaxf(__logf(p.y),        LOG_CLAMP);
    l1mp = fmaxf(__logf(1.0f - p.y), LOG_CLAMP);
    s += -(t.y * lp + (1.0f - t.y) * l1mp);
    lp   = fmaxf(__logf(p.z),        LOG_CLAMP);
    l1mp = fmaxf(__logf(1.0f - p.z), LOG_CLAMP);
    s += -(t.z * lp + (1.0f - t.z) * l1mp);
    lp   = fmaxf(__logf(p.w),        LOG_CLAMP);
    l1mp = fmaxf(__logf(1.0f - p.w), LOG_CLAMP);
    s += -(t.w * lp + (1.0f - t.w) * l1mp);
    return s;
}

__global__ void __launch_bounds__(256) bce_sum_kernel(
        const float4* __restrict__ p4,
        const float4* __restrict__ t4,
        float* __restrict__ out,
        int n4) {
    const int tid    = blockIdx.x * blockDim.x + threadIdx.x;
    const int stride = gridDim.x * blockDim.x;

    float a0 = 0.0f, a1 = 0.0f, a2 = 0.0f, a3 = 0.0f;
    int i = tid;
    // Main unrolled loop: issue all 8 loads before any dependent compute.
    for (; i + 3 * stride < n4; i += 4 * stride) {
        float4 p0 = p4[i];
        float4 p1 = p4[i + stride];
        float4 p2 = p4[i + 2 * stride];
        float4 p3 = p4[i + 3 * stride];
        float4 t0 = t4[i];
        float4 t1 = t4[i + stride];
        float4 t2 = t4[i + 2 * stride];
        float4 t3 = t4[i + 3 * stride];
        a0 += bce4(p0, t0);
        a1 += bce4(p1, t1);
        a2 += bce4(p2, t2);
        a3 += bce4(p3, t3);
    }
    // Tail (not hit for n4 = 8M with this grid, but keep it general).
    for (; i < n4; i += stride)
        a0 += bce4(p4[i], t4[i]);

    float acc = (a0 + a1) + (a2 + a3);

    // wave (64-lane) reduce
    #pragma unroll
    for (int off = 32; off > 0; off >>= 1)
        acc += __shfl_down(acc, off, 64);

    __shared__ float wave_sums[4];  // 256 threads = 4 waves
    int lane = threadIdx.x & 63;
    int wave = threadIdx.x >> 6;
    if (lane == 0) wave_sums[wave] = acc;
    __syncthreads();
    if (wave == 0) {
        float s = (lane < 4) ? wave_sums[lane] : 0.0f;
        #pragma unroll
        for (int off = 2; off > 0; off >>= 1)
            s += __shfl_down(s, off, 64);
        if (lane == 0) atomicAdd(out, s);
    }
}

extern "C" void kernel_launch(void* const* d_in, const int* in_sizes, int n_in,
                              void* d_out, int out_size, void* d_ws, size_t ws_size,
                              hipStream_t stream) {
    const float* predict = (const float*)d_in[0];
    const float* target  = (const float*)d_in[1];
    float* out = (float*)d_out;

    int n  = in_sizes[0];      // 33,554,432 (divisible by 4)
    int n4 = n / 4;

    // d_out is poisoned to 0xAA and never re-poisoned; we accumulate with
    // atomics, so zero it each call.
    hipMemsetAsync(d_out, 0, sizeof(float), stream);

    const int block = 256;
    const int grid  = 2048;    // 256 CU × 8 blocks; 4 outer iters exactly
    bce_sum_kernel<<<grid, block, 0, stream>>>(
        (const float4*)predict, (const float4*)target, out, n4);
}

// Round 3
// 50.859 us; speedup vs baseline: 1.2915x; 1.2915x over previous
//
#include <hip/hip_runtime.h>

// BCE-sum reduction over 2×128MiB fp32 inputs → scalar.
// R1/R2 post-mortem: loop restructuring (unroll×4, 8 loads in flight, 4 accs)
// changed NOTHING (65.3 vs 65.7 µs) → fixed-cost bottleneck suspected: 2048
// co-resident blocks all atomicAdd the same 4B address in a burst at the end.
// R3: two-stage reduce — per-block partials to d_ws (pure stores, no atomics),
// then a 1-block kernel sums the partials. Also: accumulate in log2 domain,
// apply -ln2 once per block.

#define NB 2048  // stage-1 grid

// max(ln x, -100) = ln2 * max(log2 x, -100/ln2)
#define LOG2_CLAMP -144.26950408889634f
#define NEG_LN2    -0.6931471805599453f

__device__ __forceinline__ float bce4_log2(float4 p, float4 t) {
    // t*lp + (1-t)*l1 = l1 + t*(lp - l1), all in log2 domain (positive sum,
    // scaled by -ln2 at block end).
    float s, lp, l1;
    lp = fmaxf(__log2f(p.x),        LOG2_CLAMP);
    l1 = fmaxf(__log2f(1.0f - p.x), LOG2_CLAMP);
    s  = l1 + t.x * (lp - l1);
    lp = fmaxf(__log2f(p.y),        LOG2_CLAMP);
    l1 = fmaxf(__log2f(1.0f - p.y), LOG2_CLAMP);
    s += l1 + t.y * (lp - l1);
    lp = fmaxf(__log2f(p.z),        LOG2_CLAMP);
    l1 = fmaxf(__log2f(1.0f - p.z), LOG2_CLAMP);
    s += l1 + t.z * (lp - l1);
    lp = fmaxf(__log2f(p.w),        LOG2_CLAMP);
    l1 = fmaxf(__log2f(1.0f - p.w), LOG2_CLAMP);
    s += l1 + t.w * (lp - l1);
    return s;
}

__device__ __forceinline__ float block_reduce(float acc) {
    #pragma unroll
    for (int off = 32; off > 0; off >>= 1)
        acc += __shfl_down(acc, off, 64);
    __shared__ float wave_sums[4];
    int lane = threadIdx.x & 63;
    int wave = threadIdx.x >> 6;
    if (lane == 0) wave_sums[wave] = acc;
    __syncthreads();
    float s = 0.0f;
    if (wave == 0) {
        s = (lane < 4) ? wave_sums[lane] : 0.0f;
        #pragma unroll
        for (int off = 2; off > 0; off >>= 1)
            s += __shfl_down(s, off, 64);
    }
    return s;  // valid in (wave 0, lane 0)
}

__global__ void __launch_bounds__(256) bce_partial_kernel(
        const float4* __restrict__ p4,
        const float4* __restrict__ t4,
        float* __restrict__ partials,
        int n4) {
    const int tid    = blockIdx.x * blockDim.x + threadIdx.x;
    const int stride = gridDim.x * blockDim.x;

    float a0 = 0.0f, a1 = 0.0f, a2 = 0.0f, a3 = 0.0f;
    int i = tid;
    for (; i + 3 * stride < n4; i += 4 * stride) {
        float4 p0 = p4[i];
        float4 p1 = p4[i + stride];
        float4 p2 = p4[i + 2 * stride];
        float4 p3 = p4[i + 3 * stride];
        float4 t0 = t4[i];
        float4 t1 = t4[i + stride];
        float4 t2 = t4[i + 2 * stride];
        float4 t3 = t4[i + 3 * stride];
        a0 += bce4_log2(p0, t0);
        a1 += bce4_log2(p1, t1);
        a2 += bce4_log2(p2, t2);
        a3 += bce4_log2(p3, t3);
    }
    for (; i < n4; i += stride)
        a0 += bce4_log2(p4[i], t4[i]);

    float s = block_reduce((a0 + a1) + (a2 + a3));
    if (threadIdx.x == 0)
        partials[blockIdx.x] = NEG_LN2 * s;   // plain store, no atomic
}

__global__ void __launch_bounds__(256) bce_final_kernel(
        const float* __restrict__ partials,
        float* __restrict__ out,
        int nb) {
    float acc = 0.0f;
    for (int i = threadIdx.x; i < nb; i += 256)
        acc += partials[i];
    float s = block_reduce(acc);
    if (threadIdx.x == 0)
        out[0] = s;   // overwrites poison; no memset needed
}

// Fallback (tiny ws): original atomic path.
__global__ void __launch_bounds__(256) bce_atomic_kernel(
        const float4* __restrict__ p4,
        const float4* __restrict__ t4,
        float* __restrict__ out,
        int n4) {
    const int tid    = blockIdx.x * blockDim.x + threadIdx.x;
    const int stride = gridDim.x * blockDim.x;
    float a = 0.0f;
    for (int i = tid; i < n4; i += stride)
        a += bce4_log2(p4[i], t4[i]);
    float s = block_reduce(a);
    if (threadIdx.x == 0)
        atomicAdd(out, NEG_LN2 * s);
}

extern "C" void kernel_launch(void* const* d_in, const int* in_sizes, int n_in,
                              void* d_out, int out_size, void* d_ws, size_t ws_size,
                              hipStream_t stream) {
    const float* predict = (const float*)d_in[0];
    const float* target  = (const float*)d_in[1];
    float* out = (float*)d_out;

    int n  = in_sizes[0];      // 33,554,432 (divisible by 4)
    int n4 = n / 4;

    if (ws_size >= NB * sizeof(float)) {
        float* partials = (float*)d_ws;
        bce_partial_kernel<<<NB, 256, 0, stream>>>(
            (const float4*)predict, (const float4*)target, partials, n4);
        bce_final_kernel<<<1, 256, 0, stream>>>(partials, out, NB);
    } else {
        hipMemsetAsync(d_out, 0, sizeof(float), stream);
        bce_atomic_kernel<<<NB, 256, 0, stream>>>(
            (const float4*)predict, (const float4*)target, out, n4);
    }
}

// Round 4
// 47.464 us; speedup vs baseline: 1.3839x; 1.0715x over previous
//
#include <hip/hip_runtime.h>

// BCE-sum reduction over 2×128MiB fp32 inputs → scalar.
// R3 removed the 2048-way same-address atomic drain (65.7→50.9 µs, matched
// prediction). Now delivered BW is ~5.6 TB/s (134 MB HBM + 134 MB L3-hit in
// ~48 µs). R4 discriminates latency-bound vs delivery-capped: unroll×8
// (16 float4 loads in flight per thread) + block-contiguous chunks.

#define NB  2048   // stage-1 grid
#define BLK 256

// max(ln x, -100) = ln2 * max(log2 x, -100/ln2); accumulate positive sum in
// log2 domain, scale by -ln2 once per block.
#define LOG2_CLAMP -144.26950408889634f
#define NEG_LN2    -0.6931471805599453f

__device__ __forceinline__ float bce4_log2(float4 p, float4 t) {
    float s, lp, l1;
    lp = fmaxf(__log2f(p.x),        LOG2_CLAMP);
    l1 = fmaxf(__log2f(1.0f - p.x), LOG2_CLAMP);
    s  = l1 + t.x * (lp - l1);
    lp = fmaxf(__log2f(p.y),        LOG2_CLAMP);
    l1 = fmaxf(__log2f(1.0f - p.y), LOG2_CLAMP);
    s += l1 + t.y * (lp - l1);
    lp = fmaxf(__log2f(p.z),        LOG2_CLAMP);
    l1 = fmaxf(__log2f(1.0f - p.z), LOG2_CLAMP);
    s += l1 + t.z * (lp - l1);
    lp = fmaxf(__log2f(p.w),        LOG2_CLAMP);
    l1 = fmaxf(__log2f(1.0f - p.w), LOG2_CLAMP);
    s += l1 + t.w * (lp - l1);
    return s;
}

__device__ __forceinline__ float block_reduce(float acc) {
    #pragma unroll
    for (int off = 32; off > 0; off >>= 1)
        acc += __shfl_down(acc, off, 64);
    __shared__ float wave_sums[4];
    int lane = threadIdx.x & 63;
    int wave = threadIdx.x >> 6;
    if (lane == 0) wave_sums[wave] = acc;
    __syncthreads();
    float s = 0.0f;
    if (wave == 0) {
        s = (lane < 4) ? wave_sums[lane] : 0.0f;
        #pragma unroll
        for (int off = 2; off > 0; off >>= 1)
            s += __shfl_down(s, off, 64);
    }
    return s;  // valid in (wave 0, lane 0)
}

__global__ void __launch_bounds__(BLK) bce_partial_kernel(
        const float4* __restrict__ p4,
        const float4* __restrict__ t4,
        float* __restrict__ partials,
        int n4) {
    // Block-contiguous chunk: block b owns [b*chunk, (b+1)*chunk).
    const int chunk = n4 / gridDim.x;               // 4096 for n4 = 8M
    const int base  = blockIdx.x * chunk;

    float a0 = 0.f, a1 = 0.f, a2 = 0.f, a3 = 0.f,
          a4 = 0.f, a5 = 0.f, a6 = 0.f, a7 = 0.f;

    int o = 0;
    // Main loop: 8 p-loads + 8 t-loads issued back-to-back (16 in flight).
    for (; o + 8 * BLK <= chunk; o += 8 * BLK) {
        int i = base + o + threadIdx.x;
        float4 p0 = p4[i];           float4 p1 = p4[i + 1 * BLK];
        float4 p2 = p4[i + 2 * BLK]; float4 p3 = p4[i + 3 * BLK];
        float4 p4v = p4[i + 4 * BLK]; float4 p5 = p4[i + 5 * BLK];
        float4 p6 = p4[i + 6 * BLK]; float4 p7 = p4[i + 7 * BLK];
        float4 t0 = t4[i];           float4 t1 = t4[i + 1 * BLK];
        float4 t2 = t4[i + 2 * BLK]; float4 t3 = t4[i + 3 * BLK];
        float4 t4v = t4[i + 4 * BLK]; float4 t5 = t4[i + 5 * BLK];
        float4 t6 = t4[i + 6 * BLK]; float4 t7 = t4[i + 7 * BLK];
        a0 += bce4_log2(p0, t0);  a1 += bce4_log2(p1, t1);
        a2 += bce4_log2(p2, t2);  a3 += bce4_log2(p3, t3);
        a4 += bce4_log2(p4v, t4v); a5 += bce4_log2(p5, t5);
        a6 += bce4_log2(p6, t6);  a7 += bce4_log2(p7, t7);
    }
    // Chunk tail (unused for the fixed shape; generality guard).
    for (; o < chunk; o += BLK) {
        int i = base + o + threadIdx.x;
        if (o + (int)threadIdx.x < chunk)
            a0 += bce4_log2(p4[i], t4[i]);
    }
    // Global tail beyond NB*chunk (unused for fixed shape): block 0 sweeps.
    if (blockIdx.x == 0) {
        for (int i = (int)gridDim.x * chunk + threadIdx.x; i < n4; i += BLK)
            a0 += bce4_log2(p4[i], t4[i]);
    }

    float s = block_reduce(((a0 + a1) + (a2 + a3)) + ((a4 + a5) + (a6 + a7)));
    if (threadIdx.x == 0)
        partials[blockIdx.x] = NEG_LN2 * s;   // plain store, no atomic
}

__global__ void __launch_bounds__(BLK) bce_final_kernel(
        const float* __restrict__ partials,
        float* __restrict__ out,
        int nb) {
    float acc = 0.0f;
    for (int i = threadIdx.x; i < nb; i += BLK)
        acc += partials[i];
    float s = block_reduce(acc);
    if (threadIdx.x == 0)
        out[0] = s;   // overwrites poison; no memset needed
}

// Fallback (tiny ws): atomic path.
__global__ void __launch_bounds__(BLK) bce_atomic_kernel(
        const float4* __restrict__ p4,
        const float4* __restrict__ t4,
        float* __restrict__ out,
        int n4) {
    const int tid    = blockIdx.x * blockDim.x + threadIdx.x;
    const int stride = gridDim.x * blockDim.x;
    float a = 0.0f;
    for (int i = tid; i < n4; i += stride)
        a += bce4_log2(p4[i], t4[i]);
    float s = block_reduce(a);
    if (threadIdx.x == 0)
        atomicAdd(out, NEG_LN2 * s);
}

extern "C" void kernel_launch(void* const* d_in, const int* in_sizes, int n_in,
                              void* d_out, int out_size, void* d_ws, size_t ws_size,
                              hipStream_t stream) {
    const float* predict = (const float*)d_in[0];
    const float* target  = (const float*)d_in[1];
    float* out = (float*)d_out;

    int n  = in_sizes[0];      // 33,554,432 (divisible by 4)
    int n4 = n / 4;

    if (ws_size >= NB * sizeof(float) && n4 >= NB) {
        float* partials = (float*)d_ws;
        bce_partial_kernel<<<NB, BLK, 0, stream>>>(
            (const float4*)predict, (const float4*)target, partials, n4);
        bce_final_kernel<<<1, BLK, 0, stream>>>(partials, out, NB);
    } else {
        hipMemsetAsync(d_out, 0, sizeof(float), stream);
        bce_atomic_kernel<<<NB, BLK, 0, stream>>>(
            (const float4*)predict, (const float4*)target, out, n4);
    }
}